// Round 1
// 1187.431 us; speedup vs baseline: 1.0694x; 1.0694x over previous
//
#include <hip/hip_runtime.h>

// HierarchicalRouter: B=32768 tokens, H=4096, 16 groups x 16 experts.
// Inputs fp32: hidden[B,H], group_w[16,H], expert_w[16,16,H].
// Output fp32 (concat): [B,256] all_expert_logits, [B] selected_experts, [B] expert_weights.
//
// fp32 end-to-end (argmax fidelity).
// R1 change: occupancy 25%->100%. H split 16 ways (was 4): 1024-thread blocks,
// 16 waves, 8192 waves total (= machine capacity). Two-round LDS reduce keeps
// static LDS < 64 KB. Epilogues via 16-lane shfl_xor butterflies (deterministic,
// first-max tie-break == jnp.argmax).

constexpr int Btok = 32768;
constexpr int Hdim = 4096;
constexpr int Gn   = 16;
constexpr int EPGn = 16;
constexpr int En   = 256;
constexpr int WV   = 16;          // waves per block (H-split)
constexpr int Hs   = Hdim / WV;   // 256 floats per wave slice
constexpr int TILE = 1024;        // tokens per kernel-2 tile

__global__ __launch_bounds__(1024, 8) void k_group(
    const float* __restrict__ hidden, const float* __restrict__ gw,
    unsigned char* __restrict__ gsel)
{
  const int lane = threadIdx.x & 63;
  // readfirstlane: prove wave-uniformity so weight loads become s_load (SGPR).
  const int wq = __builtin_amdgcn_readfirstlane((int)(threadIdx.x >> 6)); // 0..15
  const int token = blockIdx.x * 64 + lane;
  const float* hrow  = hidden + (size_t)token * Hdim + wq * Hs;
  const float* wbase = gw + wq * Hs;

  float acc[Gn];
#pragma unroll
  for (int g = 0; g < Gn; ++g) acc[g] = 0.f;

#pragma unroll 2
  for (int j = 0; j < Hs; j += 4) {
    const float4 h4 = *reinterpret_cast<const float4*>(hrow + j);
#pragma unroll
    for (int g = 0; g < Gn; ++g) {
      const float* wg = wbase + g * Hdim + j;   // uniform addr -> scalar load
      acc[g] += h4.x * wg[0] + h4.y * wg[1] + h4.z * wg[2] + h4.w * wg[3];
    }
  }

  // Two-round cross-wave reduce: waves 8..15 store, waves 0..7 add.
  __shared__ float part[8][64][Gn + 1];   // 34.8 KB, +1 pad: conflict-free
  if (wq >= 8) {
#pragma unroll
    for (int g = 0; g < Gn; ++g) part[wq - 8][lane][g] = acc[g];
  }
  __syncthreads();
  if (wq < 8) {
#pragma unroll
    for (int g = 0; g < Gn; ++g) part[wq][lane][g] += acc[g];
  }
  __syncthreads();

  // thread t -> (tok = t>>4, g = t&15): final 8-way sum + 16-lane argmax.
  const int tok = threadIdx.x >> 4;
  const int g   = threadIdx.x & 15;
  float v = 0.f;
#pragma unroll
  for (int s = 0; s < 8; ++s) v += part[s][tok][g];

  int bi = g;
#pragma unroll
  for (int off = 8; off; off >>= 1) {
    float v2 = __shfl_xor(v, off);
    int   i2 = __shfl_xor(bi, off);
    if (v2 > v || (v2 == v && i2 < bi)) { v = v2; bi = i2; }  // first-max
  }
  if (g == 0) gsel[blockIdx.x * 64 + tok] = (unsigned char)bi;
}

__global__ __launch_bounds__(1024, 8) void k_expert(
    const float* __restrict__ hidden, const float* __restrict__ ew,
    const unsigned char* __restrict__ gsel,
    float* __restrict__ out0,   // [B,256]
    float* __restrict__ out1,   // [B] selected expert (as float)
    float* __restrict__ out2)   // [B] expert weight
{
  const int g = blockIdx.x;              // 0..15
  const int tbase = blockIdx.y * TILE;

  __shared__ int   list[TILE];
  __shared__ int   cnt;
  __shared__ float part[8][64][EPGn + 1];   // 34.8 KB
  __shared__ float lrow[64][EPGn + 1];      // 4.3 KB

  if (threadIdx.x == 0) cnt = 0;
  __syncthreads();
  for (int i = threadIdx.x; i < TILE; i += 1024) {
    if ((int)gsel[tbase + i] == g) {
      int p = atomicAdd(&cnt, 1);
      list[p] = tbase + i;
    }
  }
  __syncthreads();
  const int n = cnt;

  const int lane = threadIdx.x & 63;
  const int wq = __builtin_amdgcn_readfirstlane((int)(threadIdx.x >> 6)); // 0..15
  const float* wbase = ew + ((size_t)g * EPGn) * Hdim + wq * Hs;

  for (int s0 = 0; s0 < n; s0 += 64) {
    const int ns = min(64, n - s0);
    const int token = list[s0 + ((lane < ns) ? lane : 0)];
    const float* hrow = hidden + (size_t)token * Hdim + wq * Hs;

    float acc[EPGn];
#pragma unroll
    for (int e = 0; e < EPGn; ++e) acc[e] = 0.f;

#pragma unroll 2
    for (int j = 0; j < Hs; j += 4) {
      const float4 h4 = *reinterpret_cast<const float4*>(hrow + j);
#pragma unroll
      for (int e = 0; e < EPGn; ++e) {
        const float* we = wbase + e * Hdim + j;   // uniform -> s_load
        acc[e] += h4.x * we[0] + h4.y * we[1] + h4.z * we[2] + h4.w * we[3];
      }
    }

    if (wq >= 8) {
#pragma unroll
      for (int e = 0; e < EPGn; ++e) part[wq - 8][lane][e] = acc[e];
    }
    __syncthreads();
    if (wq < 8) {
#pragma unroll
      for (int e = 0; e < EPGn; ++e) part[wq][lane][e] += acc[e];
    }
    __syncthreads();

    // thread t -> (tk = t>>4, e = t&15): final sum + softmax + argmax.
    const int tk = threadIdx.x >> 4;
    const int e  = threadIdx.x & 15;
    float l = 0.f;
#pragma unroll
    for (int s = 0; s < 8; ++s) l += part[s][tk][e];
    lrow[tk][e] = l;   // written & later read by the same wave (no barrier needed)

    float m = l;
#pragma unroll
    for (int off = 8; off; off >>= 1) m = fmaxf(m, __shfl_xor(m, off));
    float sum = __expf(l - m);
#pragma unroll
    for (int off = 8; off; off >>= 1) sum += __shfl_xor(sum, off);

    float v = l; int bi = e;
#pragma unroll
    for (int off = 8; off; off >>= 1) {
      float v2 = __shfl_xor(v, off);
      int   i2 = __shfl_xor(bi, off);
      if (v2 > v || (v2 == v && i2 < bi)) { v = v2; bi = i2; }  // first-max
    }
    if (e == 0 && tk < ns) {
      const int tok = list[s0 + tk];
      out1[tok] = (float)(g * EPGn + bi);
      out2[tok] = 1.f / sum;             // exp(max-max)/sum == top prob
    }

    // Write full 256-wide fp32 row: zeros except the selected group's block.
    // thread (r = t>>4, p = t&15): one 16-float expert block per thread.
    const int r = tk;
    const int p = e;
    if (r < ns) {
      const int tok = list[s0 + r];
      float* row = out0 + (size_t)tok * En + p * 16;
      if (p == g) {
#pragma unroll
        for (int q = 0; q < 4; ++q) {
          float4 v4;
          v4.x = lrow[r][q * 4 + 0];
          v4.y = lrow[r][q * 4 + 1];
          v4.z = lrow[r][q * 4 + 2];
          v4.w = lrow[r][q * 4 + 3];
          *reinterpret_cast<float4*>(row + q * 4) = v4;
        }
      } else {
        const float4 z = {0.f, 0.f, 0.f, 0.f};
#pragma unroll
        for (int q = 0; q < 4; ++q)
          *reinterpret_cast<float4*>(row + q * 4) = z;
      }
    }
    __syncthreads();   // protect part/lrow before next sub-tile
  }
}

extern "C" void kernel_launch(void* const* d_in, const int* in_sizes, int n_in,
                              void* d_out, int out_size, void* d_ws, size_t ws_size,
                              hipStream_t stream) {
  const float* hidden = (const float*)d_in[0];
  const float* gw     = (const float*)d_in[1];
  const float* ew     = (const float*)d_in[2];
  float* out0 = (float*)d_out;
  unsigned char* gsel = (unsigned char*)d_ws;        // 32 KB scratch

  k_group<<<Btok / 64, 1024, 0, stream>>>(hidden, gw, gsel);

  float* out1 = out0 + (size_t)Btok * En;
  float* out2 = out1 + Btok;
  k_expert<<<dim3(Gn, Btok / TILE), 1024, 0, stream>>>(
      hidden, ew, gsel, out0, out1, out2);
}